// Round 2
// baseline (904.265 us; speedup 1.0000x reference)
//
#include <hip/hip_runtime.h>
#include <hip/hip_bf16.h>

// CustomRNN: h_{t+1} = tanh([x_t | h_t] @ W_ih + b_ih), out = h_final @ W_ho + b_ho
// BATCH=512, SEQ=1024, IN=64, HID=256, CLS=10.
//
// 32 blocks x 512 threads (8 waves), one block per 16 batch rows, 1 block/CU.
// W_ih lives in registers as bf16 MFMA B-fragments (wave w owns output cols
// [32w,32w+32), interleaved per-lane pairing col0=32w+2*frow, col0+1 so the
// epilogue packs 2 bf16 per ds_write_b32).
// LDS A-panel holds ONLY h (16x256 bf16, 8KB, double-buffered, XOR-swizzled).
// x_t enters MFMA as register A-fragments loaded directly from global,
// software-pipelined 2 steps deep (unroll-2 -> no carry movs). The barrier is
// raw `s_waitcnt lgkmcnt(0); s_barrier` so in-flight x loads (vmcnt) are NOT
// drained each step (hipcc's __syncthreads would drain vmcnt(0)).

#define BATCH 512
#define SEQ   1024
#define INP   64
#define HID   256
#define CLS   10
#define ROWS  16
#define NWAVES 8
#define NTHREADS (NWAVES * 64)
#define ROWB  (HID * 2)          // 512 B per h-row in LDS
#define NKH   (HID / 32)         // 8 h k-tiles of 32

typedef short bf16x8 __attribute__((ext_vector_type(8)));
typedef float f32x4  __attribute__((ext_vector_type(4)));

static __device__ __forceinline__ unsigned short f2bf(float f) {
  __hip_bfloat16 h = __float2bfloat16(f);   // RNE
  return *reinterpret_cast<unsigned short*>(&h);
}
static __device__ __forceinline__ float bf2f(unsigned short b) {
  union { unsigned int u; float f; } v; v.u = ((unsigned int)b) << 16;
  return v.f;
}
static __device__ __forceinline__ float fast_exp2(float x) {
#if __has_builtin(__builtin_amdgcn_exp2f)
  return __builtin_amdgcn_exp2f(x);
#else
  return __exp2f(x);
#endif
}
static __device__ __forceinline__ float fast_rcp(float x) {
#if __has_builtin(__builtin_amdgcn_rcpf)
  return __builtin_amdgcn_rcpf(x);
#else
  return 1.0f / x;
#endif
}
// tanh(x) = 1 - 2/(exp(2x)+1); saturates correctly for |x| large.
static __device__ __forceinline__ float fast_tanh(float x) {
  float e = fast_exp2(x * 2.8853900817779268f);
  return 1.0f - 2.0f * fast_rcp(1.0f + e);
}

// XOR swizzle: row stride 512 B (bank-period multiple); 16 same-column lanes
// of a ds_read_b128 spread across 8 distinct 16B slots (2-way = free).
static __device__ __forceinline__ int swz(int row, int byteInRow) {
  return row * ROWB + (byteInRow ^ ((row & 7) << 4));
}

// lgkmcnt(0) drains ds_writes/reads; vmcnt deliberately NOT drained so the
// 2-step-deep x prefetch stays in flight across the barrier.
#define BARRIER() asm volatile("s_waitcnt lgkmcnt(0)\n\ts_barrier" ::: "memory")

// One scan step: read h-frags from SRC, MFMA with register-resident W and
// register-resident x frags (X0..X3, loaded 2 steps ago), reload X0..X3 for
// step T+2, tanh epilogue into DST, barrier.
#define STEP(T, X0, X1, X2, X3, SRC, DST) do {                                  \
    bf16x8 a[NKH];                                                              \
    _Pragma("unroll")                                                           \
    for (int kt = 0; kt < NKH; ++kt)                                            \
      a[kt] = *(const bf16x8*)&(SRC)[swz(frow, kt * 64 + g * 16)];              \
    bf16x8 ax0, ax1;                                                            \
    _Pragma("unroll")                                                           \
    for (int i = 0; i < 4; ++i) {                                               \
      ax0[i]     = (short)f2bf(X0[i]);                                          \
      ax0[i + 4] = (short)f2bf(X1[i]);                                          \
      ax1[i]     = (short)f2bf(X2[i]);                                          \
      ax1[i + 4] = (short)f2bf(X3[i]);                                          \
    }                                                                           \
    { int tn = (T) + 2; tn = (tn < SEQ) ? tn : (SEQ - 1);                       \
      const float* p = xbase + (size_t)tn * INP;                                \
      X0 = *(const f32x4*)(p);      X1 = *(const f32x4*)(p + 4);                \
      X2 = *(const f32x4*)(p + 32); X3 = *(const f32x4*)(p + 36); }             \
    f32x4 acc0a = {bias0, bias0, bias0, bias0}, acc0b = {0.f, 0.f, 0.f, 0.f};   \
    f32x4 acc1a = {bias1, bias1, bias1, bias1}, acc1b = {0.f, 0.f, 0.f, 0.f};   \
    acc0a = __builtin_amdgcn_mfma_f32_16x16x32_bf16(ax0, bwx[0][0], acc0a, 0, 0, 0); \
    acc0b = __builtin_amdgcn_mfma_f32_16x16x32_bf16(ax1, bwx[1][0], acc0b, 0, 0, 0); \
    acc1a = __builtin_amdgcn_mfma_f32_16x16x32_bf16(ax0, bwx[0][1], acc1a, 0, 0, 0); \
    acc1b = __builtin_amdgcn_mfma_f32_16x16x32_bf16(ax1, bwx[1][1], acc1b, 0, 0, 0); \
    _Pragma("unroll")                                                           \
    for (int kt = 0; kt < NKH; kt += 2) {                                       \
      acc0a = __builtin_amdgcn_mfma_f32_16x16x32_bf16(a[kt],     bwh[kt][0],     acc0a, 0, 0, 0); \
      acc0b = __builtin_amdgcn_mfma_f32_16x16x32_bf16(a[kt + 1], bwh[kt + 1][0], acc0b, 0, 0, 0); \
      acc1a = __builtin_amdgcn_mfma_f32_16x16x32_bf16(a[kt],     bwh[kt][1],     acc1a, 0, 0, 0); \
      acc1b = __builtin_amdgcn_mfma_f32_16x16x32_bf16(a[kt + 1], bwh[kt + 1][1], acc1b, 0, 0, 0); \
    }                                                                           \
    f32x4 s0 = acc0a + acc0b, s1 = acc1a + acc1b;                               \
    _Pragma("unroll")                                                           \
    for (int j = 0; j < 4; ++j) {                                               \
      unsigned int pk = (unsigned int)f2bf(fast_tanh(s0[j]))                    \
                      | ((unsigned int)f2bf(fast_tanh(s1[j])) << 16);           \
      *(unsigned int*)&(DST)[swz(g * 4 + j, col0 * 2)] = pk;                    \
    }                                                                           \
    BARRIER();                                                                  \
  } while (0)

__global__ __launch_bounds__(NTHREADS, 2)
void rnn_scan_kernel(const float* __restrict__ x,
                     const float* __restrict__ W_ih,
                     const float* __restrict__ b_ih,
                     const float* __restrict__ W_ho,
                     const float* __restrict__ b_ho,
                     float* __restrict__ out) {
  __shared__ __align__(128) unsigned char sA[2][ROWS * ROWB];  // 2 x 8 KB

  const int tid  = threadIdx.x;
  const int lane = tid & 63;
  const int wave = tid >> 6;
  const int b0   = blockIdx.x * ROWS;

  const int g    = (lane >> 4) & 3;   // k-group within fragment
  const int frow = lane & 15;         // A-row (loads) / tile-col (B/D)
  const int n0   = wave * 32;
  const int col0 = n0 + 2 * frow;     // lane's even output column

  // ---- x prefetch registers (2-step pipeline), issue loads first
  const float* xbase = x + (size_t)(b0 + frow) * SEQ * INP + g * 8;
  f32x4 xe0 = *(const f32x4*)(xbase + 0);           // t = 0
  f32x4 xe1 = *(const f32x4*)(xbase + 4);
  f32x4 xe2 = *(const f32x4*)(xbase + 32);
  f32x4 xe3 = *(const f32x4*)(xbase + 36);
  f32x4 xo0 = *(const f32x4*)(xbase + INP + 0);     // t = 1
  f32x4 xo1 = *(const f32x4*)(xbase + INP + 4);
  f32x4 xo2 = *(const f32x4*)(xbase + INP + 32);
  f32x4 xo3 = *(const f32x4*)(xbase + INP + 36);

  // ---- Preload W_ih as B-fragments (bf16). B: col = lane&15-tile col,
  // k = 8*(lane>>4)+i within each K=32 tile. Interleaved col pairing.
  bf16x8 bwx[2][2];       // x part, W rows [0,64)
  bf16x8 bwh[NKH][2];     // h part, W rows [64,320)
  const float bias0 = b_ih[col0];
  const float bias1 = b_ih[col0 + 1];
#pragma unroll
  for (int nt = 0; nt < 2; ++nt) {
    const int col = col0 + nt;
#pragma unroll
    for (int kx = 0; kx < 2; ++kx) {
      bf16x8 v;
#pragma unroll
      for (int i = 0; i < 8; ++i)
        v[i] = (short)f2bf(W_ih[(size_t)(kx * 32 + g * 8 + i) * HID + col]);
      bwx[kx][nt] = v;
    }
#pragma unroll
    for (int kt = 0; kt < NKH; ++kt) {
      bf16x8 v;
#pragma unroll
      for (int i = 0; i < 8; ++i)
        v[i] = (short)f2bf(W_ih[(size_t)(INP + kt * 32 + g * 8 + i) * HID + col]);
      bwh[kt][nt] = v;
    }
  }

  // ---- h_0 = 0 in buffer 0 (zeros are swizzle-invariant)
  for (int i = tid; i < ROWS * ROWB / 4; i += NTHREADS)
    ((unsigned int*)sA[0])[i] = 0u;
  BARRIER();

  // ---- Main scan: unroll-2 so x-prefetch registers rotate statically
#pragma unroll 1
  for (int t = 0; t < SEQ; t += 2) {
    STEP(t,     xe0, xe1, xe2, xe3, sA[0], sA[1]);
    STEP(t + 1, xo0, xo1, xo2, xo3, sA[1], sA[0]);
  }
  // h_final (h_1024) is in sA[0]

  // ---- Head: out = h_final @ W_ho + b_ho (16 rows x 10 cols per block)
  if (tid < ROWS * CLS) {
    const int row = tid / CLS, cl = tid % CLS;
    float s = b_ho[cl];
#pragma unroll 8
    for (int k = 0; k < HID; ++k) {
      const unsigned short hb = *(const unsigned short*)&sA[0][swz(row, k * 2)];
      s += bf2f(hb) * W_ho[(size_t)k * CLS + cl];
    }
    out[(size_t)(b0 + row) * CLS + cl] = s;
  }
}

extern "C" void kernel_launch(void* const* d_in, const int* in_sizes, int n_in,
                              void* d_out, int out_size, void* d_ws, size_t ws_size,
                              hipStream_t stream) {
  const float* x    = (const float*)d_in[0];
  const float* W_ih = (const float*)d_in[1];
  const float* b_ih = (const float*)d_in[2];
  const float* W_ho = (const float*)d_in[3];
  const float* b_ho = (const float*)d_in[4];
  float* out = (float*)d_out;

  rnn_scan_kernel<<<BATCH / ROWS, NTHREADS, 0, stream>>>(x, W_ih, b_ih, W_ho, b_ho, out);
}

// Round 3
// 677.171 us; speedup vs baseline: 1.3354x; 1.3354x over previous
//
#include <hip/hip_runtime.h>
#include <hip/hip_bf16.h>

// CustomRNN: h_{t+1} = tanh([x_t | h_t] @ W_ih + b_ih), out = h_final @ W_ho + b_ho
// BATCH=512, SEQ=1024, IN=64, HID=256, CLS=10.
//
// 128 blocks x 512 threads (8 waves, 2/SIMD). Each block owns FOUR batch rows
// (M-padding in the 16x16 MFMA is free per-CU: tile count is row-independent,
// so 4-row blocks spread the fixed per-step MFMA work over 4x more CUs while
// making every LDS a-frag read 4-distinct-rows + broadcast, ~3x cheaper).
// Wave w owns output cols [32w,32w+32), paired col0=32w+2*frow / col0+1.
// W_ih (pre-scaled by 2*log2(e) to fold tanh's multiply) lives in registers
// as bf16 B-fragments. h panel: 4x256 bf16 (2KB) double-buffered, XOR-swizzled.
// x panel: 4x64 bf16 (512B) double-buffered, staged global->reg->LDS with a
// full step of latency cover. Barrier = raw `s_waitcnt lgkmcnt(0); s_barrier`
// so in-flight global x loads (vmcnt) are never drained.

#define BATCH 512
#define SEQ   1024
#define INP   64
#define HID   256
#define CLS   10
#define ROWS  4
#define NBLK  (BATCH / ROWS)       // 128
#define NWAVES 8
#define NTHREADS (NWAVES * 64)     // 512
#define HROWB (HID * 2)            // 512 B per h-row
#define XROWB (INP * 2)            // 128 B per x-row
#define NKT   10                   // k-tiles of 32: 2 x-tiles + 8 h-tiles
#define TSCALE 2.8853900817779268f // 2*log2(e), folded into W_ih and b_ih

typedef short bf16x8 __attribute__((ext_vector_type(8)));
typedef float f32x4  __attribute__((ext_vector_type(4)));

static __device__ __forceinline__ unsigned short f2bf(float f) {
  __hip_bfloat16 h = __float2bfloat16(f);   // RNE
  return *reinterpret_cast<unsigned short*>(&h);
}
static __device__ __forceinline__ float bf2f(unsigned short b) {
  union { unsigned int u; float f; } v; v.u = ((unsigned int)b) << 16;
  return v.f;
}
static __device__ __forceinline__ unsigned int cvt_pk_bf16(float lo, float hi) {
  unsigned int r;
  asm("v_cvt_pk_bf16_f32 %0, %1, %2" : "=v"(r) : "v"(lo), "v"(hi));
  return r;
}
static __device__ __forceinline__ float fast_exp2(float x) {
#if __has_builtin(__builtin_amdgcn_exp2f)
  return __builtin_amdgcn_exp2f(x);
#else
  return __exp2f(x);
#endif
}
static __device__ __forceinline__ float fast_rcp(float x) {
#if __has_builtin(__builtin_amdgcn_rcpf)
  return __builtin_amdgcn_rcpf(x);
#else
  return 1.0f / x;
#endif
}

// XOR swizzle: row strides (512/128 B) are bank-period multiples, so the 4
// rows would alias the same banks; XOR bits 4-5 of the in-row byte with the
// row index -> 4 distinct 16B slots per read, conflict-free (+ same-address
// broadcast for the frow>=4 duplicate lanes).
static __device__ __forceinline__ int swzh(int row, int b) {
  return row * HROWB + (b ^ ((row & 3) << 4));
}
static __device__ __forceinline__ int swzx(int row, int b) {
  return row * XROWB + (b ^ ((row & 3) << 4));
}

// Drain LDS ops only; global x prefetch (vmcnt) stays in flight.
#define BARRIER() asm volatile("s_waitcnt lgkmcnt(0)\n\ts_barrier" ::: "memory")

#define STEP(T, RB) do {                                                        \
    bf16x8 a[NKT];                                                              \
    a[0] = *(const bf16x8*)&sX[RB][swzx(frow & 3, g * 16)];                     \
    a[1] = *(const bf16x8*)&sX[RB][swzx(frow & 3, 64 + g * 16)];                \
    _Pragma("unroll")                                                           \
    for (int kt = 0; kt < 8; ++kt)                                              \
      a[kt + 2] = *(const bf16x8*)&sH[RB][swzh(frow & 3, kt * 64 + g * 16)];    \
    /* stage x_{T+1} (loaded a full step ago) into sX[RB^1]; prefetch x_{T+2} */\
    if (tid < ROWS * INP) {                                                     \
      *(unsigned short*)&sX[RB ^ 1][swzx(srow, scol * 2)] = f2bf(xr);           \
      int tn = (T) + 2; tn = tn < SEQ ? tn : SEQ - 1;                           \
      xr = x[xoff + (size_t)tn * INP];                                          \
    }                                                                           \
    f32x4 acc0a = {bias0, bias0, bias0, bias0}, acc0b = {0.f, 0.f, 0.f, 0.f};   \
    f32x4 acc1a = {bias1, bias1, bias1, bias1}, acc1b = {0.f, 0.f, 0.f, 0.f};   \
    _Pragma("unroll")                                                           \
    for (int kt = 0; kt < NKT; kt += 2) {                                       \
      acc0a = __builtin_amdgcn_mfma_f32_16x16x32_bf16(a[kt],     bw[kt][0],     acc0a, 0, 0, 0); \
      acc1a = __builtin_amdgcn_mfma_f32_16x16x32_bf16(a[kt],     bw[kt][1],     acc1a, 0, 0, 0); \
      acc0b = __builtin_amdgcn_mfma_f32_16x16x32_bf16(a[kt + 1], bw[kt + 1][0], acc0b, 0, 0, 0); \
      acc1b = __builtin_amdgcn_mfma_f32_16x16x32_bf16(a[kt + 1], bw[kt + 1][1], acc1b, 0, 0, 0); \
    }                                                                           \
    /* D rows 0-3 live in g==0 lanes only; rows 4-15 are padding garbage */     \
    if (g == 0) {                                                               \
      f32x4 s0 = acc0a + acc0b, s1 = acc1a + acc1b;                             \
      _Pragma("unroll")                                                         \
      for (int j = 0; j < 4; ++j) {                                             \
        /* pre-act already scaled by 2*log2(e): tanh = 1 - 2/(1+exp2(s)) */     \
        float t0 = 1.f - 2.f * fast_rcp(1.f + fast_exp2(s0[j]));                \
        float t1 = 1.f - 2.f * fast_rcp(1.f + fast_exp2(s1[j]));                \
        *(unsigned int*)&sH[RB ^ 1][swzh(j, col0 * 2)] = cvt_pk_bf16(t0, t1);   \
      }                                                                         \
    }                                                                           \
    BARRIER();                                                                  \
  } while (0)

__global__ __launch_bounds__(NTHREADS, 2)
void rnn_scan_kernel(const float* __restrict__ x,
                     const float* __restrict__ W_ih,
                     const float* __restrict__ b_ih,
                     const float* __restrict__ W_ho,
                     const float* __restrict__ b_ho,
                     float* __restrict__ out) {
  __shared__ __align__(128) unsigned char sH[2][ROWS * HROWB];  // 2 x 2 KB
  __shared__ __align__(128) unsigned char sX[2][ROWS * XROWB];  // 2 x 512 B

  const int tid  = threadIdx.x;
  const int lane = tid & 63;
  const int wave = tid >> 6;
  const int b0   = blockIdx.x * ROWS;

  const int g    = (lane >> 4) & 3;   // k-group within fragment
  const int frow = lane & 15;         // A-row (loads) / tile col (B/D)
  const int col0 = wave * 32 + 2 * frow;

  // x staging geometry (waves 0-3 only; uniform row per wave)
  const int srow = tid >> 6;          // 0..3 when tid < 256
  const int scol = tid & 63;
  const size_t xoff = (size_t)(b0 + (srow & 3)) * SEQ * INP + scol;

  // ---- Preload W_ih as B-fragments (bf16, pre-scaled). B: tile-col = lane&15,
  // k = 8*(lane>>4)+i. k-order [x(64) | h(256)] matches W_ih row order.
  bf16x8 bw[NKT][2];
  const float bias0 = b_ih[col0] * TSCALE;
  const float bias1 = b_ih[col0 + 1] * TSCALE;
#pragma unroll
  for (int nt = 0; nt < 2; ++nt) {
#pragma unroll
    for (int kt = 0; kt < NKT; ++kt) {
      bf16x8 v;
#pragma unroll
      for (int i = 0; i < 8; ++i)
        v[i] = (short)f2bf(W_ih[(size_t)(kt * 32 + g * 8 + i) * HID + col0 + nt] * TSCALE);
      bw[kt][nt] = v;
    }
  }

  // ---- Prologue: zero h buf0, stage x_0, preload x_1 into xr
  float xr = 0.f;
  if (tid < ROWS * INP) {
    float x0 = x[xoff];                       // t = 0
    *(unsigned short*)&sX[0][swzx(srow, scol * 2)] = f2bf(x0);
    xr = x[xoff + (size_t)INP];               // t = 1
  }
  for (int i = tid; i < ROWS * HROWB / 4; i += NTHREADS)
    ((unsigned int*)sH[0])[i] = 0u;           // zeros are swizzle-invariant
  BARRIER();

  // ---- Main scan: one barrier per step, unroll-2 for static buffer flip
#pragma unroll 1
  for (int t = 0; t < SEQ; t += 2) {
    STEP(t,     0);
    STEP(t + 1, 1);
  }
  // SEQ even -> h_final in sH[0]

  // ---- Head: out = h_final @ W_ho + b_ho (4 rows x 10 cols per block)
  if (tid < ROWS * CLS) {
    const int row = tid / CLS, cl = tid - row * CLS;
    float s = b_ho[cl];
#pragma unroll 4
    for (int kb = 0; kb < HID / 8; ++kb) {
      bf16x8 hv = *(const bf16x8*)&sH[0][swzh(row, kb * 16)];
#pragma unroll
      for (int i = 0; i < 8; ++i)
        s += bf2f((unsigned short)hv[i]) * W_ho[(size_t)(kb * 8 + i) * CLS + cl];
    }
    out[(size_t)(b0 + row) * CLS + cl] = s;
  }
}

extern "C" void kernel_launch(void* const* d_in, const int* in_sizes, int n_in,
                              void* d_out, int out_size, void* d_ws, size_t ws_size,
                              hipStream_t stream) {
  const float* x    = (const float*)d_in[0];
  const float* W_ih = (const float*)d_in[1];
  const float* b_ih = (const float*)d_in[2];
  const float* W_ho = (const float*)d_in[3];
  const float* b_ho = (const float*)d_in[4];
  float* out = (float*)d_out;

  rnn_scan_kernel<<<NBLK, NTHREADS, 0, stream>>>(x, W_ih, b_ih, W_ho, b_ho, out);
}